// Round 19
// baseline (2338.834 us; speedup 1.0000x reference)
//
#include <hip/hip_runtime.h>

// SparseWeights: y = x @ (W_dense + scatter(sparse))^T + bias
// Round 19: 2 blocks/CU. All 256^2 kernels since r6 used 128KiB LDS = 1
// block/CU -> per-tile vmcnt+barrier stalls are uncovered (no m114 overlap).
// This kernel: 256x256, BK=32, LDS 2x(A16K+B16K)=64KiB -> 2 blocks/CU,
// 4 waves/SIMD. Same per-K LDS/MFMA/stage economy as r18; r2's
// MEASURED-conflict-free 64B-row swizzle (quad = cq ^ ((fr>>1)&3)).
// Swapped-operand float4 epilogue + setprio kept (r16/r17 measured).

typedef __attribute__((ext_vector_type(8))) __bf16 bf16x8;
typedef __attribute__((ext_vector_type(4))) float f32x4;
typedef __attribute__((ext_vector_type(8))) unsigned short u16x8;

#define BARRIER()   asm volatile("s_barrier" ::: "memory")
#define WAITLGKM0() asm volatile("s_waitcnt lgkmcnt(0)" ::: "memory")
#define WAITVM0()   asm volatile("s_waitcnt vmcnt(0)" ::: "memory")
#define SCHED0()    __builtin_amdgcn_sched_barrier(0)

__device__ __forceinline__ unsigned short f2bf(float f) {
  unsigned int u = __builtin_bit_cast(unsigned int, f);
  u += 0x7FFFu + ((u >> 16) & 1u);   // round-to-nearest-even
  return (unsigned short)(u >> 16);
}

// ---- prepass 1/3: f32 -> bf16 bulk convert (vectorized x8) ----
__global__ __launch_bounds__(256) void cvt_f32_bf16(
    const float* __restrict__ s, unsigned short* __restrict__ d, long n8) {
  long i = (long)blockIdx.x * blockDim.x + threadIdx.x;
  const long stride = (long)gridDim.x * blockDim.x;
  for (; i < n8; i += stride) {
    const float4* sp = (const float4*)(s + i * 8);
    float4 a = sp[0];
    float4 b = sp[1];
    u16x8 o;
    o[0] = f2bf(a.x); o[1] = f2bf(a.y); o[2] = f2bf(a.z); o[3] = f2bf(a.w);
    o[4] = f2bf(b.x); o[5] = f2bf(b.y); o[6] = f2bf(b.z); o[7] = f2bf(b.w);
    *(u16x8*)(d + i * 8) = o;
  }
}

// ---- prepass 2/3: scatter sparse values into bf16 W (after W-cvt) ----
__global__ __launch_bounds__(256) void sparse_scatter(
    const float* __restrict__ dense, const float* __restrict__ vals,
    const int* __restrict__ rows, const int* __restrict__ cols,
    unsigned short* __restrict__ Wb, int nnz, int K) {
  int i = blockIdx.x * blockDim.x + threadIdx.x;
  if (i < nnz) {
    size_t off = (size_t)rows[i] * (size_t)K + (size_t)cols[i];
    Wb[off] = f2bf(dense[off] + vals[i]);
  }
}

// =====================================================================
// 256x256 GEMM, 512 threads = 8 waves (2Mx4N), wave tile 128x64 =
// acc[8][4] of 16x16x32 frags, BK=32 (one bf16x8 per frag). LDS:
// 2 x (A 16K @0 + B 16K @16384) = 64 KiB -> 2 blocks/CU. Rows 64 B =
// 4 quads; LDS quad q of row r holds global quad q ^ ((r>>1)&3)
// (r2's swizzle: 0 bank conflicts measured at this exact row width;
// 2 lanes/bank-group per quarter-wave). Pre-swizzled source + swizzled
// ds_read (rule #21).
// Tile t (buf = t&1): stage-all(t+1 -> buf^1) [4 gl_lds]; read a03+b
// [8]; lgkm0; H0 = 16 MFMA; read a47 [4] (shared A-buf, after H0);
// lgkm0; H1 = 16 MFMA; vmcnt(0) {stage(t+1), ~620cy old — residual
// stall covered by the co-resident block}; BARRIER.
// Ledger: buf(t) staged @t-1 start, drained @t-1 vmcnt0, published
// @t-1 barrier. WAW: stage(t+1)->buf^1, last read by tile t-1 (lgkm0
// before t-1's barrier < issue @t). Tail t=NT-1: no stage, vmcnt free.
// MFMA swapped (b,a) -> lane holds 4 consecutive C cols -> float4 store.
// =====================================================================
__global__ __launch_bounds__(512, 4) void gemm19(
    const unsigned short* __restrict__ A,   // [Tm][K] bf16
    const unsigned short* __restrict__ B,   // [Mn][K] bf16
    const float* __restrict__ bias,
    float* __restrict__ C,
    int Tm, int Mn, int K) {
  extern __shared__ __align__(16) char smem[];   // 2 x 32768

  const int tid  = threadIdx.x;
  const int lane = tid & 63;
  const int wid  = tid >> 6;
  const int wm = (wid >> 2) * 128;
  const int wn = (wid & 3) * 64;

  // T1: XCD-aware bijective swizzle (nwg = 512, % 8 == 0)
  const int nwg = gridDim.x;
  int bid = blockIdx.x;
  if ((nwg & 7) == 0) bid = (bid & 7) * (nwg >> 3) + (bid >> 3);
  const int ntn = Mn >> 8;
  const int bm0 = (bid / ntn) << 8;
  const int bn0 = (bid % ntn) << 8;

  const int NT = K >> 5;             // K-tiles of 32 (=128)

  // ---- staging: thread t -> LDS byte t*16 (+8192 for call c=1)
  // = row (t>>2)+128c, quad t&3. Source quad = (t&3)^((t>>3)&3)
  // [inverse of the read swizzle; (r>>1)&3 of row (t>>2) = (t>>3)&3].
  const int sr  = tid >> 2;                          // 0..127
  const int sq8 = ((tid & 3) ^ ((tid >> 3) & 3)) * 8;
  const unsigned short* Asrc = A + (size_t)(bm0 + sr) * K + sq8;
  const unsigned short* Bsrc = B + (size_t)(bn0 + sr) * K + sq8;
  const size_t r128 = (size_t)128 * K;
  const int ldst = tid * 16;

#define STAGEALL(NB, KO) do {                                                    \
    __builtin_amdgcn_global_load_lds(                                            \
      (const __attribute__((address_space(1))) void*)(Asrc + (KO)),              \
      (__attribute__((address_space(3))) void*)(smem + (NB) + ldst), 16, 0, 0);  \
    __builtin_amdgcn_global_load_lds(                                            \
      (const __attribute__((address_space(1))) void*)(Asrc + r128 + (KO)),       \
      (__attribute__((address_space(3))) void*)(smem + (NB) + 8192 + ldst), 16, 0, 0); \
    __builtin_amdgcn_global_load_lds(                                            \
      (const __attribute__((address_space(1))) void*)(Bsrc + (KO)),              \
      (__attribute__((address_space(3))) void*)(smem + (NB) + 16384 + ldst), 16, 0, 0); \
    __builtin_amdgcn_global_load_lds(                                            \
      (const __attribute__((address_space(1))) void*)(Bsrc + r128 + (KO)),       \
      (__attribute__((address_space(3))) void*)(smem + (NB) + 24576 + ldst), 16, 0, 0); \
  } while (0)

  // ---- read offsets: frag (row R, cq) -> byte R*64 + ((cq^((R>>1)&3))<<4)
  // R = base16 + fr, base16 mult of 16 -> (R>>1)&3 = (fr>>1)&3.
  const int fr = lane & 15, cq = lane >> 4;
  const int qoff = ((cq ^ ((fr >> 1) & 3)) << 4);
  const int arow = (wm + fr) * 64 + qoff;            // + m*1024
  const int brow = 16384 + (wn + fr) * 64 + qoff;    // + n*1024

  f32x4 acc[8][4] = {};
  bf16x8 a[4], b[4];

  // ---- prologue: stage tile 0 into buf 0 ----
  STAGEALL(0, 0);
  WAITVM0();
  BARRIER();

#pragma unroll 2
  for (int t = 0; t < NT; ++t) {
    const char* buf = smem + (t & 1) * 32768;
    const int nb = ((t & 1) ^ 1) * 32768;

    // ---- stage tile t+1 at start (max headroom within dbuf) ----
    if (t + 1 < NT) STAGEALL(nb, (t + 1) * 32);

    // ---- H0: a03 x b[0..3] ----
#pragma unroll
    for (int m = 0; m < 4; ++m)
      a[m] = *(const bf16x8*)(buf + arow + m * 1024);
#pragma unroll
    for (int n = 0; n < 4; ++n)
      b[n] = *(const bf16x8*)(buf + brow + n * 1024);
    SCHED0();
    WAITLGKM0();
    SCHED0();
    __builtin_amdgcn_s_setprio(1);
#pragma unroll
    for (int m = 0; m < 4; ++m)
#pragma unroll
      for (int n = 0; n < 4; ++n)
        acc[m][n] = __builtin_amdgcn_mfma_f32_16x16x32_bf16(b[n], a[m], acc[m][n], 0, 0, 0);
    __builtin_amdgcn_s_setprio(0);
    SCHED0();

    // ---- H1: a47 x b[0..3] (shared A-buf reload after H0) ----
#pragma unroll
    for (int m = 0; m < 4; ++m)
      a[m] = *(const bf16x8*)(buf + arow + (m + 4) * 1024);
    SCHED0();
    WAITLGKM0();
    SCHED0();
    __builtin_amdgcn_s_setprio(1);
#pragma unroll
    for (int m = 0; m < 4; ++m)
#pragma unroll
      for (int n = 0; n < 4; ++n)
        acc[m + 4][n] = __builtin_amdgcn_mfma_f32_16x16x32_bf16(b[n], a[m], acc[m + 4][n], 0, 0, 0);
    __builtin_amdgcn_s_setprio(0);

    WAITVM0();     // stage(t+1); residual latency covered by 2nd block
    BARRIER();
  }
#undef STAGEALL

  // ---- epilogue (swapped layout): lane (fr,cq) frag (m,n) holds C cols
  // wn+n*16+cq*4 .. +3 at row wm+m*16+fr -> one float4 store each. ----
#pragma unroll
  for (int n = 0; n < 4; ++n) {
    const int colb = bn0 + wn + n * 16 + cq * 4;
    const float4 bv = *(const float4*)(bias + colb);
#pragma unroll
    for (int m = 0; m < 8; ++m) {
      const int row = bm0 + wm + m * 16 + fr;
      float4 v;
      v.x = acc[m][n][0] + bv.x;
      v.y = acc[m][n][1] + bv.y;
      v.z = acc[m][n][2] + bv.z;
      v.w = acc[m][n][3] + bv.w;
      *(float4*)(C + (size_t)row * Mn + colb) = v;
    }
  }
}

extern "C" void kernel_launch(void* const* d_in, const int* in_sizes, int n_in,
                              void* d_out, int out_size, void* d_ws, size_t ws_size,
                              hipStream_t stream) {
  const float* x     = (const float*)d_in[0];
  const float* dw    = (const float*)d_in[1];
  const float* bias  = (const float*)d_in[2];
  const float* sv    = (const float*)d_in[3];
  const int*   rows  = (const int*)d_in[4];
  const int*   cols  = (const int*)d_in[5];
  float* out = (float*)d_out;

  const int  Mn = in_sizes[2];                       // 4096
  const long wElems = (long)in_sizes[1];             // M*K
  const int  K  = (int)(wElems / Mn);                // 4096
  const long xElems = (long)in_sizes[0];             // T*K
  const int  Tm = (int)(xElems / K);                 // 8192
  const int  nnz = in_sizes[3];

  unsigned short* Wb = (unsigned short*)d_ws;        // [M*K] bf16
  unsigned short* Xb = Wb + wElems;                  // [T*K] bf16

  cvt_f32_bf16<<<2048, 256, 0, stream>>>(dw, Wb, wElems / 8);
  sparse_scatter<<<(nnz + 255) / 256, 256, 0, stream>>>(dw, sv, rows, cols, Wb, nnz, K);
  cvt_f32_bf16<<<2048, 256, 0, stream>>>(x, Xb, xElems / 8);

  dim3 grid((Tm >> 8) * (Mn >> 8));                  // 32*16 = 512
  gemm19<<<grid, 512, 65536, stream>>>(Xb, Wb, bias, out, Tm, Mn, K);
}

// Round 20
// 302.084 us; speedup vs baseline: 7.7423x; 7.7423x over previous
//
#include <hip/hip_runtime.h>

// SparseWeights: y = x @ (W_dense + scatter(sparse))^T + bias
// FINAL (= r18, session best: 296.5us total, GEMM 264-269us @46% MfmaUtil).
// GEMM: 256x256 tile, lead-1 counted-lgkm register pipeline, conflict-free
// XOR-swizzled LDS (0 conflicts measured), global_load_lds staging with
// 1-tile lead, swapped-operand MFMA -> float4 C-stores, setprio quadrants.
// Prepass: two separate HBM-peak bf16 cvts + unique-index scatter.
// r19 lesson (final): acc[8][4] = 128 AGPR on the unified file -> >=170
// regs/wave -> 1 block/CU is structural; launch_bounds(512,4) spills acc
// (VGPR=64, FETCH 4.4GB, MfmaUtil 5%). Do not cap below ~170.

typedef __attribute__((ext_vector_type(8))) __bf16 bf16x8;
typedef __attribute__((ext_vector_type(4))) float f32x4;
typedef __attribute__((ext_vector_type(8))) unsigned short u16x8;

#define BARRIER()   asm volatile("s_barrier" ::: "memory")
#define WAITLGKM(n) asm volatile("s_waitcnt lgkmcnt(" #n ")" ::: "memory")
#define WAITVM0()   asm volatile("s_waitcnt vmcnt(0)" ::: "memory")
#define SCHED0()    __builtin_amdgcn_sched_barrier(0)

__device__ __forceinline__ unsigned short f2bf(float f) {
  unsigned int u = __builtin_bit_cast(unsigned int, f);
  u += 0x7FFFu + ((u >> 16) & 1u);   // round-to-nearest-even
  return (unsigned short)(u >> 16);
}

// ---- prepass 1/3: f32 -> bf16 bulk convert (vectorized x8) ----
__global__ __launch_bounds__(256) void cvt_f32_bf16(
    const float* __restrict__ s, unsigned short* __restrict__ d, long n8) {
  long i = (long)blockIdx.x * blockDim.x + threadIdx.x;
  const long stride = (long)gridDim.x * blockDim.x;
  for (; i < n8; i += stride) {
    const float4* sp = (const float4*)(s + i * 8);
    float4 a = sp[0];
    float4 b = sp[1];
    u16x8 o;
    o[0] = f2bf(a.x); o[1] = f2bf(a.y); o[2] = f2bf(a.z); o[3] = f2bf(a.w);
    o[4] = f2bf(b.x); o[5] = f2bf(b.y); o[6] = f2bf(b.z); o[7] = f2bf(b.w);
    *(u16x8*)(d + i * 8) = o;
  }
}

// ---- prepass 2/3: scatter sparse values into bf16 W (after W-cvt) ----
__global__ __launch_bounds__(256) void sparse_scatter(
    const float* __restrict__ dense, const float* __restrict__ vals,
    const int* __restrict__ rows, const int* __restrict__ cols,
    unsigned short* __restrict__ Wb, int nnz, int K) {
  int i = blockIdx.x * blockDim.x + threadIdx.x;
  if (i < nnz) {
    size_t off = (size_t)rows[i] * (size_t)K + (size_t)cols[i];
    Wb[off] = f2bf(dense[off] + vals[i]);
  }
}

// =====================================================================
// 256x256 GEMM, 512 threads = 8 waves (2Mx4N), wave tile 128x64 =
// acc[8][4] of 16x16x32 frags, BK=64 (kk=0,1). LDS 2 x (A 32K + B 32K)
// = 128 KiB dbuf. Rows 128 B = 8 quads; LDS quad q of row r holds global
// quad q^(r&7) (pre-swizzled source, swizzled read; 0 conflicts measured).
//
// Lead-1 pipeline per tile t (buf = t&1):
//  X1 (end of prev iter): MFMA Q11(t-1); read a03(t)+b01(t) [12];
//     stage-all(t+2) [8 gl_lds]
//  X2: read b23(t) [4]; lgkm(4) {drains 12, keeps b23}; Q00
//  X3: lgkm(0) {b23, covered}; Q01; read a47(t) [8] into shared A-buf
//  X4: lgkm(0) {a47}; Q10; vmcnt(0) {stage(t+1), 1 iter old}; BARRIER
//
// MFMA operands swapped: acc = mfma(b, a, acc) -> lane holds 4
// consecutive C columns -> float4 C-stores. setprio around quadrants.
// =====================================================================
__global__ __launch_bounds__(512, 2) void gemm18(
    const unsigned short* __restrict__ A,   // [Tm][K] bf16
    const unsigned short* __restrict__ B,   // [Mn][K] bf16
    const float* __restrict__ bias,
    float* __restrict__ C,
    int Tm, int Mn, int K) {
  extern __shared__ __align__(16) char smem[];   // 2 x 65536

  const int tid  = threadIdx.x;
  const int lane = tid & 63;
  const int wid  = tid >> 6;
  const int wm = (wid >> 2) * 128;
  const int wn = (wid & 3) * 64;

  // T1: XCD-aware bijective swizzle (nwg = 512, % 8 == 0)
  const int nwg = gridDim.x;
  int bid = blockIdx.x;
  if ((nwg & 7) == 0) bid = (bid & 7) * (nwg >> 3) + (bid >> 3);
  const int ntn = Mn >> 8;
  const int bm0 = (bid / ntn) << 8;
  const int bn0 = (bid % ntn) << 8;

  const int NT = K >> 6;             // K-tiles of 64

  // ---- staging (verified mapping, r6-r18) ----
  const int sr  = tid >> 3;                          // 0..63
  const int gq8 = ((tid & 7) ^ (sr & 7)) * 8;        // pre-swizzled elem off
  const unsigned short* Asrc = A + (size_t)(bm0 + sr) * K + gq8;
  const unsigned short* Bsrc = B + (size_t)(bn0 + sr) * K + gq8;
  const size_t r64 = (size_t)64 * K;
  const int ldst = tid * 16;

#define STAGEH(SRC, H, LDSB, KOFF) do {                                          \
    __builtin_amdgcn_global_load_lds(                                            \
      (const __attribute__((address_space(1))) void*)((SRC) + (size_t)(H)*2*r64 + (KOFF)), \
      (__attribute__((address_space(3))) void*)(smem + (LDSB) + ldst), 16, 0, 0);\
    __builtin_amdgcn_global_load_lds(                                            \
      (const __attribute__((address_space(1))) void*)((SRC) + (size_t)(H)*2*r64 + r64 + (KOFF)), \
      (__attribute__((address_space(3))) void*)(smem + (LDSB) + 8192 + ldst), 16, 0, 0); \
  } while (0)

#define STAGEALL(NB, KO) do {                                                    \
    STAGEH(Asrc, 0, (NB), (KO));                                                 \
    STAGEH(Asrc, 1, (NB) + 16384, (KO));                                         \
    STAGEH(Bsrc, 0, (NB) + 32768, (KO));                                         \
    STAGEH(Bsrc, 1, (NB) + 49152, (KO));                                         \
  } while (0)

  // ---- read offsets: frag (row R, kk, cq) -> byte R*128 + ((kk*4+cq)^(R&7))*16
  const int fr = lane & 15, cq = lane >> 4;
  const int f7 = fr & 7;
  const int q0 = ((cq ^ f7) << 4);          // kk = 0
  const int q1 = (((4 + cq) ^ f7) << 4);    // kk = 1
  const int arow = (wm + fr) * 128;
  const int brow = (wn + fr) * 128;

  f32x4 acc[8][4] = {};
  bf16x8 Aq0[4], Aq1[4];                    // shared a03 / a47
  bf16x8 b1q0[2], b1q1[2], b2q0[2], b2q1[2];

#define READ12(BUF) do {                                                         \
    _Pragma("unroll")                                                            \
    for (int m = 0; m < 4; ++m) {                                                \
      Aq0[m] = *(const bf16x8*)((BUF) + arow + m * 2048 + q0);                   \
      Aq1[m] = *(const bf16x8*)((BUF) + arow + m * 2048 + q1);                   \
    }                                                                            \
    _Pragma("unroll")                                                            \
    for (int n = 0; n < 2; ++n) {                                                \
      b1q0[n] = *(const bf16x8*)((BUF) + 32768 + brow + n * 2048 + q0);          \
      b1q1[n] = *(const bf16x8*)((BUF) + 32768 + brow + n * 2048 + q1);          \
    }                                                                            \
  } while (0)

#define READB23(BUF) do {                                                        \
    _Pragma("unroll")                                                            \
    for (int n = 0; n < 2; ++n) {                                                \
      b2q0[n] = *(const bf16x8*)((BUF) + 32768 + brow + (n + 2) * 2048 + q0);    \
      b2q1[n] = *(const bf16x8*)((BUF) + 32768 + brow + (n + 2) * 2048 + q1);    \
    }                                                                            \
  } while (0)

#define READA47(BUF) do {                                                        \
    _Pragma("unroll")                                                            \
    for (int m = 0; m < 4; ++m) {                                                \
      Aq0[m] = *(const bf16x8*)((BUF) + arow + (m + 4) * 2048 + q0);             \
      Aq1[m] = *(const bf16x8*)((BUF) + arow + (m + 4) * 2048 + q1);             \
    }                                                                            \
  } while (0)

// Swapped operands + setprio: D = b x a = C^T fragment.
#define QUAD(MB, NB, BQ0, BQ1) do {                                              \
    __builtin_amdgcn_s_setprio(1);                                               \
    _Pragma("unroll")                                                            \
    for (int m = 0; m < 4; ++m)                                                  \
      _Pragma("unroll")                                                          \
      for (int n = 0; n < 2; ++n) {                                              \
        acc[m+(MB)][n+(NB)] = __builtin_amdgcn_mfma_f32_16x16x32_bf16(           \
            BQ0[n], Aq0[m], acc[m+(MB)][n+(NB)], 0, 0, 0);                       \
        acc[m+(MB)][n+(NB)] = __builtin_amdgcn_mfma_f32_16x16x32_bf16(           \
            BQ1[n], Aq1[m], acc[m+(MB)][n+(NB)], 0, 0, 0);                       \
      }                                                                          \
    __builtin_amdgcn_s_setprio(0);                                               \
  } while (0)

  // ---- prologue: stage tile 0; publish; lead-1 reads of tile 0; stage 1 ----
  STAGEALL(0, 0);
  WAITVM0();
  BARRIER();
  READ12(smem);
  SCHED0();
  if (NT > 1) STAGEALL(65536, 64);
  SCHED0();

  for (int t = 0; t < NT; ++t) {
    const char* buf = smem + (t & 1) * 65536;

    // ---- X2: b23 reads; counted lgkm(4); Q00 ----
    READB23(buf);
    SCHED0();
    WAITLGKM(4);          // drain a03+b01 (12); b23 (4) stays in flight
    SCHED0();
    QUAD(0, 0, b1q0, b1q1);
    SCHED0();

    // ---- X3: lgkm(0) (b23, covered by Q00); Q01; a47 reads after ----
    WAITLGKM(0);
    SCHED0();
    QUAD(0, 2, b2q0, b2q1);
    SCHED0();
    READA47(buf);         // overwrites shared A after Q01 latched a03
    SCHED0();

    // ---- X4: lgkm(0) (a47); Q10; drain stages; publish ----
    WAITLGKM(0);
    SCHED0();
    QUAD(4, 0, b1q0, b1q1);
    WAITVM0();            // stage(t+1): issued one full iter ago -> free
    BARRIER();

    // ---- X1 of next frame: Q11; lead-1 reads(t+1); stage(t+2) ----
    QUAD(4, 2, b2q0, b2q1);
    SCHED0();
    if (t + 1 < NT) {
      const char* nbuf = smem + ((t + 1) & 1) * 65536;
      READ12(nbuf);       // overwrites A (a47 latched by Q11) + b01
      SCHED0();
      if (t + 2 < NT) STAGEALL((t & 1) * 65536, (t + 2) * 64);
      SCHED0();
    }
  }
#undef QUAD
#undef READA47
#undef READB23
#undef READ12
#undef STAGEALL
#undef STAGEH

  // ---- epilogue (swapped layout): lane (fr,cq) frag (m,n) holds C cols
  // wn+n*16+cq*4 .. +3 at row wm+m*16+fr -> one float4 store each. ----
#pragma unroll
  for (int n = 0; n < 4; ++n) {
    const int colb = bn0 + wn + n * 16 + cq * 4;
    const float4 bv = *(const float4*)(bias + colb);
#pragma unroll
    for (int m = 0; m < 8; ++m) {
      const int row = bm0 + wm + m * 16 + fr;
      float4 v;
      v.x = acc[m][n][0] + bv.x;
      v.y = acc[m][n][1] + bv.y;
      v.z = acc[m][n][2] + bv.z;
      v.w = acc[m][n][3] + bv.w;
      *(float4*)(C + (size_t)row * Mn + colb) = v;
    }
  }
}

extern "C" void kernel_launch(void* const* d_in, const int* in_sizes, int n_in,
                              void* d_out, int out_size, void* d_ws, size_t ws_size,
                              hipStream_t stream) {
  const float* x     = (const float*)d_in[0];
  const float* dw    = (const float*)d_in[1];
  const float* bias  = (const float*)d_in[2];
  const float* sv    = (const float*)d_in[3];
  const int*   rows  = (const int*)d_in[4];
  const int*   cols  = (const int*)d_in[5];
  float* out = (float*)d_out;

  const int  Mn = in_sizes[2];                       // 4096
  const long wElems = (long)in_sizes[1];             // M*K
  const int  K  = (int)(wElems / Mn);                // 4096
  const long xElems = (long)in_sizes[0];             // T*K
  const int  Tm = (int)(xElems / K);                 // 8192
  const int  nnz = in_sizes[3];

  unsigned short* Wb = (unsigned short*)d_ws;        // [M*K] bf16
  unsigned short* Xb = Wb + wElems;                  // [T*K] bf16

  cvt_f32_bf16<<<2048, 256, 0, stream>>>(dw, Wb, wElems / 8);
  sparse_scatter<<<(nnz + 255) / 256, 256, 0, stream>>>(dw, sv, rows, cols, Wb, nnz, K);
  cvt_f32_bf16<<<2048, 256, 0, stream>>>(x, Xb, xElems / 8);

  dim3 grid((Tm >> 8) * (Mn >> 8));                  // 32*16 = 512
  gemm18<<<grid, 512, 131072, stream>>>(Xb, Wb, bias, out, Tm, Mn, K);
}

// Round 21
// 300.728 us; speedup vs baseline: 7.7773x; 1.0045x over previous
//
#include <hip/hip_runtime.h>

// SparseWeights: y = x @ (W_dense + scatter(sparse))^T + bias
// Round 21: r18 (session best, 296.5us; reproduced 302.1 — noise +-3us) with
// one zero-risk micro-change: STAGEALL(t+2) issued immediately after the X4
// barrier (before Q11/READ12) -> stage loads ~150cy older at the next X4
// vmcnt(0) drain. All hazards unchanged (stage still after the publishing
// barrier; no reg overlap with Q11; lgkm counts unaffected).
// Session constraints (measured): 8 schedule families -> 43-48% MfmaUtil;
// acc[8][4]=128 AGPR on unified RF -> 1 block/CU structural (r19 spill);
// fp8/i8 excluded by 0.154 abs threshold arithmetic; prepass at HBM peak.

typedef __attribute__((ext_vector_type(8))) __bf16 bf16x8;
typedef __attribute__((ext_vector_type(4))) float f32x4;
typedef __attribute__((ext_vector_type(8))) unsigned short u16x8;

#define BARRIER()   asm volatile("s_barrier" ::: "memory")
#define WAITLGKM(n) asm volatile("s_waitcnt lgkmcnt(" #n ")" ::: "memory")
#define WAITVM0()   asm volatile("s_waitcnt vmcnt(0)" ::: "memory")
#define SCHED0()    __builtin_amdgcn_sched_barrier(0)

__device__ __forceinline__ unsigned short f2bf(float f) {
  unsigned int u = __builtin_bit_cast(unsigned int, f);
  u += 0x7FFFu + ((u >> 16) & 1u);   // round-to-nearest-even
  return (unsigned short)(u >> 16);
}

// ---- prepass 1/3: f32 -> bf16 bulk convert (vectorized x8) ----
__global__ __launch_bounds__(256) void cvt_f32_bf16(
    const float* __restrict__ s, unsigned short* __restrict__ d, long n8) {
  long i = (long)blockIdx.x * blockDim.x + threadIdx.x;
  const long stride = (long)gridDim.x * blockDim.x;
  for (; i < n8; i += stride) {
    const float4* sp = (const float4*)(s + i * 8);
    float4 a = sp[0];
    float4 b = sp[1];
    u16x8 o;
    o[0] = f2bf(a.x); o[1] = f2bf(a.y); o[2] = f2bf(a.z); o[3] = f2bf(a.w);
    o[4] = f2bf(b.x); o[5] = f2bf(b.y); o[6] = f2bf(b.z); o[7] = f2bf(b.w);
    *(u16x8*)(d + i * 8) = o;
  }
}

// ---- prepass 2/3: scatter sparse values into bf16 W (after W-cvt) ----
__global__ __launch_bounds__(256) void sparse_scatter(
    const float* __restrict__ dense, const float* __restrict__ vals,
    const int* __restrict__ rows, const int* __restrict__ cols,
    unsigned short* __restrict__ Wb, int nnz, int K) {
  int i = blockIdx.x * blockDim.x + threadIdx.x;
  if (i < nnz) {
    size_t off = (size_t)rows[i] * (size_t)K + (size_t)cols[i];
    Wb[off] = f2bf(dense[off] + vals[i]);
  }
}

// =====================================================================
// 256x256 GEMM, 512 threads = 8 waves (2Mx4N), wave tile 128x64 =
// acc[8][4] of 16x16x32 frags, BK=64 (kk=0,1). LDS 2 x (A 32K + B 32K)
// = 128 KiB dbuf. Rows 128 B = 8 quads; LDS quad q of row r holds global
// quad q^(r&7) (pre-swizzled source, swizzled read; 0 conflicts measured).
//
// Lead-1 pipeline per tile t (buf = t&1):
//  X1 (end of prev iter): stage-all(t+2) [8 gl_lds, earliest-safe point];
//     MFMA Q11(t-1); read a03(t)+b01(t) [12]
//  X2: read b23(t) [4]; lgkm(4) {drains 12, keeps b23}; Q00
//  X3: lgkm(0) {b23, covered}; Q01; read a47(t) [8] into shared A-buf
//  X4: lgkm(0) {a47}; Q10; vmcnt(0) {stage(t+1), >1 iter old}; BARRIER
//
// MFMA operands swapped: acc = mfma(b, a, acc) -> lane holds 4
// consecutive C columns -> float4 C-stores. setprio around quadrants.
// =====================================================================
__global__ __launch_bounds__(512, 2) void gemm21(
    const unsigned short* __restrict__ A,   // [Tm][K] bf16
    const unsigned short* __restrict__ B,   // [Mn][K] bf16
    const float* __restrict__ bias,
    float* __restrict__ C,
    int Tm, int Mn, int K) {
  extern __shared__ __align__(16) char smem[];   // 2 x 65536

  const int tid  = threadIdx.x;
  const int lane = tid & 63;
  const int wid  = tid >> 6;
  const int wm = (wid >> 2) * 128;
  const int wn = (wid & 3) * 64;

  // T1: XCD-aware bijective swizzle (nwg = 512, % 8 == 0)
  const int nwg = gridDim.x;
  int bid = blockIdx.x;
  if ((nwg & 7) == 0) bid = (bid & 7) * (nwg >> 3) + (bid >> 3);
  const int ntn = Mn >> 8;
  const int bm0 = (bid / ntn) << 8;
  const int bn0 = (bid % ntn) << 8;

  const int NT = K >> 6;             // K-tiles of 64

  // ---- staging (verified mapping, r6-r20) ----
  const int sr  = tid >> 3;                          // 0..63
  const int gq8 = ((tid & 7) ^ (sr & 7)) * 8;        // pre-swizzled elem off
  const unsigned short* Asrc = A + (size_t)(bm0 + sr) * K + gq8;
  const unsigned short* Bsrc = B + (size_t)(bn0 + sr) * K + gq8;
  const size_t r64 = (size_t)64 * K;
  const int ldst = tid * 16;

#define STAGEH(SRC, H, LDSB, KOFF) do {                                          \
    __builtin_amdgcn_global_load_lds(                                            \
      (const __attribute__((address_space(1))) void*)((SRC) + (size_t)(H)*2*r64 + (KOFF)), \
      (__attribute__((address_space(3))) void*)(smem + (LDSB) + ldst), 16, 0, 0);\
    __builtin_amdgcn_global_load_lds(                                            \
      (const __attribute__((address_space(1))) void*)((SRC) + (size_t)(H)*2*r64 + r64 + (KOFF)), \
      (__attribute__((address_space(3))) void*)(smem + (LDSB) + 8192 + ldst), 16, 0, 0); \
  } while (0)

#define STAGEALL(NB, KO) do {                                                    \
    STAGEH(Asrc, 0, (NB), (KO));                                                 \
    STAGEH(Asrc, 1, (NB) + 16384, (KO));                                         \
    STAGEH(Bsrc, 0, (NB) + 32768, (KO));                                         \
    STAGEH(Bsrc, 1, (NB) + 49152, (KO));                                         \
  } while (0)

  // ---- read offsets: frag (row R, kk, cq) -> byte R*128 + ((kk*4+cq)^(R&7))*16
  const int fr = lane & 15, cq = lane >> 4;
  const int f7 = fr & 7;
  const int q0 = ((cq ^ f7) << 4);          // kk = 0
  const int q1 = (((4 + cq) ^ f7) << 4);    // kk = 1
  const int arow = (wm + fr) * 128;
  const int brow = (wn + fr) * 128;

  f32x4 acc[8][4] = {};
  bf16x8 Aq0[4], Aq1[4];                    // shared a03 / a47
  bf16x8 b1q0[2], b1q1[2], b2q0[2], b2q1[2];

#define READ12(BUF) do {                                                         \
    _Pragma("unroll")                                                            \
    for (int m = 0; m < 4; ++m) {                                                \
      Aq0[m] = *(const bf16x8*)((BUF) + arow + m * 2048 + q0);                   \
      Aq1[m] = *(const bf16x8*)((BUF) + arow + m * 2048 + q1);                   \
    }                                                                            \
    _Pragma("unroll")                                                            \
    for (int n = 0; n < 2; ++n) {                                                \
      b1q0[n] = *(const bf16x8*)((BUF) + 32768 + brow + n * 2048 + q0);          \
      b1q1[n] = *(const bf16x8*)((BUF) + 32768 + brow + n * 2048 + q1);          \
    }                                                                            \
  } while (0)

#define READB23(BUF) do {                                                        \
    _Pragma("unroll")                                                            \
    for (int n = 0; n < 2; ++n) {                                                \
      b2q0[n] = *(const bf16x8*)((BUF) + 32768 + brow + (n + 2) * 2048 + q0);    \
      b2q1[n] = *(const bf16x8*)((BUF) + 32768 + brow + (n + 2) * 2048 + q1);    \
    }                                                                            \
  } while (0)

#define READA47(BUF) do {                                                        \
    _Pragma("unroll")                                                            \
    for (int m = 0; m < 4; ++m) {                                                \
      Aq0[m] = *(const bf16x8*)((BUF) + arow + (m + 4) * 2048 + q0);             \
      Aq1[m] = *(const bf16x8*)((BUF) + arow + (m + 4) * 2048 + q1);             \
    }                                                                            \
  } while (0)

// Swapped operands + setprio: D = b x a = C^T fragment.
#define QUAD(MB, NB, BQ0, BQ1) do {                                              \
    __builtin_amdgcn_s_setprio(1);                                               \
    _Pragma("unroll")                                                            \
    for (int m = 0; m < 4; ++m)                                                  \
      _Pragma("unroll")                                                          \
      for (int n = 0; n < 2; ++n) {                                              \
        acc[m+(MB)][n+(NB)] = __builtin_amdgcn_mfma_f32_16x16x32_bf16(           \
            BQ0[n], Aq0[m], acc[m+(MB)][n+(NB)], 0, 0, 0);                       \
        acc[m+(MB)][n+(NB)] = __builtin_amdgcn_mfma_f32_16x16x32_bf16(           \
            BQ1[n], Aq1[m], acc[m+(MB)][n+(NB)], 0, 0, 0);                       \
      }                                                                          \
    __builtin_amdgcn_s_setprio(0);                                               \
  } while (0)

  // ---- prologue: stage tile 0; publish; stage 1; lead-1 reads of tile 0 ----
  STAGEALL(0, 0);
  WAITVM0();
  BARRIER();
  if (NT > 1) STAGEALL(65536, 64);
  SCHED0();
  READ12(smem);
  SCHED0();

  for (int t = 0; t < NT; ++t) {
    const char* buf = smem + (t & 1) * 65536;

    // ---- X2: b23 reads; counted lgkm(4); Q00 ----
    READB23(buf);
    SCHED0();
    WAITLGKM(4);          // drain a03+b01 (12); b23 (4) stays in flight
    SCHED0();
    QUAD(0, 0, b1q0, b1q1);
    SCHED0();

    // ---- X3: lgkm(0) (b23, covered by Q00); Q01; a47 reads after ----
    WAITLGKM(0);
    SCHED0();
    QUAD(0, 2, b2q0, b2q1);
    SCHED0();
    READA47(buf);         // overwrites shared A after Q01 latched a03
    SCHED0();

    // ---- X4: lgkm(0) (a47); Q10; drain stages; publish ----
    WAITLGKM(0);
    SCHED0();
    QUAD(4, 0, b1q0, b1q1);
    WAITVM0();            // stage(t+1): issued >1 full iter ago -> free
    BARRIER();

    // ---- X1 of next frame: stage(t+2) at earliest-safe point; Q11;
    //      lead-1 reads(t+1) ----
    if (t + 2 < NT) {
      STAGEALL((t & 1) * 65536, (t + 2) * 64);   // buf(t) safe post-barrier
      SCHED0();
    }
    QUAD(4, 2, b2q0, b2q1);
    SCHED0();
    if (t + 1 < NT) {
      const char* nbuf = smem + ((t + 1) & 1) * 65536;
      READ12(nbuf);       // overwrites A (a47 latched by Q11) + b01
      SCHED0();
    }
  }
#undef QUAD
#undef READA47
#undef READB23
#undef READ12
#undef STAGEALL
#undef STAGEH

  // ---- epilogue (swapped layout): lane (fr,cq) frag (m,n) holds C cols
  // wn+n*16+cq*4 .. +3 at row wm+m*16+fr -> one float4 store each. ----
#pragma unroll
  for (int n = 0; n < 4; ++n) {
    const int colb = bn0 + wn + n * 16 + cq * 4;
    const float4 bv = *(const float4*)(bias + colb);
#pragma unroll
    for (int m = 0; m < 8; ++m) {
      const int row = bm0 + wm + m * 16 + fr;
      float4 v;
      v.x = acc[m][n][0] + bv.x;
      v.y = acc[m][n][1] + bv.y;
      v.z = acc[m][n][2] + bv.z;
      v.w = acc[m][n][3] + bv.w;
      *(float4*)(C + (size_t)row * Mn + colb) = v;
    }
  }
}

extern "C" void kernel_launch(void* const* d_in, const int* in_sizes, int n_in,
                              void* d_out, int out_size, void* d_ws, size_t ws_size,
                              hipStream_t stream) {
  const float* x     = (const float*)d_in[0];
  const float* dw    = (const float*)d_in[1];
  const float* bias  = (const float*)d_in[2];
  const float* sv    = (const float*)d_in[3];
  const int*   rows  = (const int*)d_in[4];
  const int*   cols  = (const int*)d_in[5];
  float* out = (float*)d_out;

  const int  Mn = in_sizes[2];                       // 4096
  const long wElems = (long)in_sizes[1];             // M*K
  const int  K  = (int)(wElems / Mn);                // 4096
  const long xElems = (long)in_sizes[0];             // T*K
  const int  Tm = (int)(xElems / K);                 // 8192
  const int  nnz = in_sizes[3];

  unsigned short* Wb = (unsigned short*)d_ws;        // [M*K] bf16
  unsigned short* Xb = Wb + wElems;                  // [T*K] bf16

  cvt_f32_bf16<<<2048, 256, 0, stream>>>(dw, Wb, wElems / 8);
  sparse_scatter<<<(nnz + 255) / 256, 256, 0, stream>>>(dw, sv, rows, cols, Wb, nnz, K);
  cvt_f32_bf16<<<2048, 256, 0, stream>>>(x, Xb, xElems / 8);

  dim3 grid((Tm >> 8) * (Mn >> 8));                  // 32*16 = 512
  gemm21<<<grid, 512, 131072, stream>>>(Xb, Wb, bias, out, Tm, Mn, K);
}